// Round 1
// 688.361 us; speedup vs baseline: 1.0395x; 1.0395x over previous
//
#include <hip/hip_runtime.h>

// DiffeqSolver: 49 RK4(3/8) steps of y' = W2 @ tanh(W1 @ y + b1) + b2
// 6144 rows, dim 128 (123+5 aug), hidden 256. Output (3,2048,50,128) fp32.
//
// Round 4: producer/consumer wave specialization + 2-group software pipeline.
//  - Waves 0-3 ("A") hold W1 split-frags only; compute H^T = tanh(W1.Y^T+b1).
//    Waves 4-7 ("B") hold W2 split-frags only; compute K^T = W2.H^T+b2, do the
//    RK4(3/8) fold in registers/LDS, build the next eval point, and write out.
//  - 24 rows split into two independent 12-row groups (16-row MFMA tiles),
//    skewed by one barrier interval: every interval A does H(g) while B does
//    K+fold+build(1-g) -> MFMA and VALU pipes overlap (waves w / w+4 share a
//    SIMD). One barrier per interval, 393 intervals total.
//  - Per-wave operand reuse doubled (4 A-tiles / 2 B-tiles per frag read):
//    LDS fragment traffic halved vs round 3.
//  - Split precision unchanged (validated): x = hi(f16) + 2^-11*lo(f16),
//    3 MFMA products, separate correction accumulator.

typedef _Float16 half8  __attribute__((ext_vector_type(8)));
typedef _Float16 half4  __attribute__((ext_vector_type(4)));
typedef float    floatx4 __attribute__((ext_vector_type(4)));

#define NBLK 256
#define DIM  128
#define HID  256
#define GROWS 12          // valid rows per group (2 groups x 12 = 24/block)
#define YH   136          // yf row stride (halfwords): slot-uniform frag reads
#define HH   264          // hf row stride (halfwords)
#define PS   132          // st_p/st_u/st_r row stride (words)
#define NTAU 393          // 2*196 evals + 1 pipeline bubble
#define LOSCALE 2048.0f
#define LOINV   (1.0f/2048.0f)

__device__ __forceinline__ float fast_tanh(float x) {
    float e = __expf(2.0f * x);
    return 1.0f - 2.0f * __builtin_amdgcn_rcpf(e + 1.0f);
}

struct h2 { _Float16 hi, lo; };
__device__ __forceinline__ h2 split16(float v) {
    h2 r;
    r.hi = (_Float16)v;
    r.lo = (_Float16)((v - (float)r.hi) * LOSCALE);
    return r;
}

__global__ __launch_bounds__(512, 2)
void ode_pipe_kernel(const float* __restrict__ fp,      // (3,2048,123)
                     const float* __restrict__ tsteps,  // (50)
                     const float* __restrict__ W1,      // (256,128)
                     const float* __restrict__ b1,      // (256)
                     const float* __restrict__ W2,      // (128,256)
                     const float* __restrict__ b2,      // (128)
                     float* __restrict__ out)           // (3,2048,50,128)
{
    // eval-point B-frags, per group (written by B-waves, read by A-waves)
    __shared__ __align__(16) _Float16 yfh[2][16*YH], yfl[2][16*YH];
    // H^T B-frags, per group (written by A-waves, read by B-waves)
    __shared__ __align__(16) _Float16 hfh[2][16*HH], hfl[2][16*HH];
    // same-wave layout exchange C-layout -> frag-layout (B-waves only)
    __shared__ __align__(16) float st_p[16*PS];
    // RK state folds (B-waves only): st_r = k1 then D=k1-k2; st_u = U accum
    __shared__ __align__(16) float st_u[2*16*PS];
    __shared__ __align__(16) float st_r[2*16*PS];
    __shared__ float ts_l[64];

    const int tid  = threadIdx.x;
    const int wave = tid >> 6;
    const int lane = tid & 63;
    const int n16  = lane & 15;
    const int quad = lane >> 4;
    const int blk  = blockIdx.x;

    if (tid < 50) ts_l[tid] = tsteps[tid];

    if (wave < 4) {
        // ================= producer A: H^T = tanh(W1 . Y^T + b1) ===========
        // wave owns h-rows [64*wave, 64*wave+64): 4 tiles of 16.
        half8 w1h[4][4], w1l[4][4];   // [i][kt]
        floatx4 bias1[4];
#pragma unroll
        for (int i = 0; i < 4; ++i) {
            bias1[i] = *(const floatx4*)(b1 + 64*wave + 16*i + 4*quad);
#pragma unroll
            for (int kt = 0; kt < 4; ++kt) {
                const float* p = W1 + (64*wave + 16*i + n16)*DIM + kt*32 + quad*8;
#pragma unroll
                for (int j = 0; j < 8; ++j) {
                    h2 sp = split16(p[j]);
                    w1h[i][kt][j] = sp.hi;
                    w1l[i][kt][j] = sp.lo;
                }
            }
        }
        const int ybase = n16*YH + quad*8;
        const int hbase = n16*HH + 64*wave + 4*quad;
        __syncthreads();                       // matches B prologue barrier
        for (int tau = 0; tau < NTAU; ++tau) {
            if (tau < NTAU-1) {
                const int g = tau & 1;
                floatx4 aM[4], aC[4];
#pragma unroll
                for (int i = 0; i < 4; ++i) {
                    aM[i] = bias1[i];
                    aC[i] = (floatx4){0.f,0.f,0.f,0.f};
                }
                __builtin_amdgcn_s_setprio(1);
#pragma unroll
                for (int kt = 0; kt < 4; ++kt) {
                    half8 ybh = *(const half8*)&yfh[g][ybase + kt*32];
                    half8 ybl = *(const half8*)&yfl[g][ybase + kt*32];
#pragma unroll
                    for (int i = 0; i < 4; ++i) {
                        aM[i] = __builtin_amdgcn_mfma_f32_16x16x32_f16(w1h[i][kt], ybh, aM[i], 0,0,0);
                        aC[i] = __builtin_amdgcn_mfma_f32_16x16x32_f16(w1l[i][kt], ybh, aC[i], 0,0,0);
                        aC[i] = __builtin_amdgcn_mfma_f32_16x16x32_f16(w1h[i][kt], ybl, aC[i], 0,0,0);
                    }
                }
                __builtin_amdgcn_s_setprio(0);
                // tanh + publish H^T frags (per-lane b64, 4 consecutive h)
#pragma unroll
                for (int i = 0; i < 4; ++i) {
                    half4 th, tl;
#pragma unroll
                    for (int r = 0; r < 4; ++r) {
                        const float a = aM[i][r] + LOINV*aC[i][r];
                        h2 sp = split16(fast_tanh(a));
                        th[r] = sp.hi; tl[r] = sp.lo;
                    }
                    *(half4*)&hfh[g][hbase + 16*i] = th;
                    *(half4*)&hfl[g][hbase + 16*i] = tl;
                }
            }
            __syncthreads();
        }
    } else {
        // ===== consumer B: K^T = W2 . H^T + b2 ; RK fold ; build yf ========
        // wave owns d-rows [32*wb, 32*wb+32): 2 tiles of 16.
        const int wb = wave - 4;
        half8 w2h[2][8], w2l[2][8];   // [j][kt]
        floatx4 bias2[2];
#pragma unroll
        for (int j = 0; j < 2; ++j) {
            bias2[j] = *(const floatx4*)(b2 + 32*wb + 16*j + 4*quad);
#pragma unroll
            for (int kt = 0; kt < 8; ++kt) {
                const float* p = W2 + (32*wb + 16*j + n16)*HID + kt*32 + quad*8;
#pragma unroll
                for (int jj = 0; jj < 8; ++jj) {
                    h2 sp = split16(p[jj]);
                    w2h[j][kt][jj] = sp.hi;
                    w2l[j][kt][jj] = sp.lo;
                }
            }
        }
        // initial state, C-layout: lane(n16,quad) holds d=32wb+16j+4quad+r, row n16
        floatx4 yg0[2], yg1[2];
#pragma unroll
        for (int g = 0; g < 2; ++g) {
#pragma unroll
            for (int j = 0; j < 2; ++j) {
                floatx4 v = (floatx4){0.f,0.f,0.f,0.f};
                if (n16 < GROWS) {
                    const int gr = blk*24 + g*GROWS + n16;
#pragma unroll
                    for (int r = 0; r < 4; ++r) {
                        const int d = 32*wb + 16*j + 4*quad + r;
                        if (d < 123) v[r] = fp[gr*123 + d];
                    }
                }
                if (g == 0) yg0[j] = v; else yg1[j] = v;
            }
        }
        // t = 0 output
        if (n16 < GROWS) {
#pragma unroll
            for (int g = 0; g < 2; ++g) {
                const int gr = blk*24 + g*GROWS + n16;
                float* po = out + ((size_t)gr*50)*DIM + 32*wb + 4*quad;
                *(floatx4*)&po[0]  = (g==0) ? yg0[0] : yg1[0];
                *(floatx4*)&po[16] = (g==0) ? yg0[1] : yg1[1];
            }
        }

        const int pwr = n16*PS + 32*wb + 4*quad;   // C-layout slot (+16*j)
        const int prd = n16*PS + 32*wb + 8*quad;   // frag-layout read
        const int ywr = n16*YH + 32*wb + 8*quad;   // yf frag write

        // C-layout p -> st_p -> frag-layout -> split -> yf[g].
        // Same-wave LDS RAW only (each wave reads only its own d-slice).
        auto publish_point = [&](int g, const floatx4* p) {
            *(floatx4*)&st_p[pwr]      = p[0];
            *(floatx4*)&st_p[pwr + 16] = p[1];
            float v[8];
            *(floatx4*)&v[0] = *(const floatx4*)&st_p[prd];
            *(floatx4*)&v[4] = *(const floatx4*)&st_p[prd + 4];
            half8 hi, lo;
#pragma unroll
            for (int jj = 0; jj < 8; ++jj) {
                h2 sp = split16(v[jj]);
                hi[jj] = sp.hi; lo[jj] = sp.lo;
            }
            *(half8*)&yfh[g][ywr] = hi;
            *(half8*)&yfl[g][ywr] = lo;
        };

        publish_point(0, yg0);       // e0 eval point = y0, both groups
        publish_point(1, yg1);

        auto fold_build = [&](floatx4 (&y)[2], const floatx4* kv, int g,
                              int e, float hstep, int s) {
            floatx4 p[2];
            const int uidx = g*(16*PS) + pwr;
            const float h3 = hstep*(1.0f/3.0f);
            if (e == 0) {            // k1: save, p2 = y + h/3 k1
#pragma unroll
                for (int j = 0; j < 2; ++j) {
                    *(floatx4*)&st_r[uidx + 16*j] = kv[j];
                    p[j] = y[j] + h3*kv[j];
                }
            } else if (e == 1) {     // k2: U=k1+3k2, D=k1-k2, p3 = y+h(k2-k1/3)
#pragma unroll
                for (int j = 0; j < 2; ++j) {
                    floatx4 r1 = *(const floatx4*)&st_r[uidx + 16*j];
                    *(floatx4*)&st_u[uidx + 16*j] = r1 + 3.0f*kv[j];
                    *(floatx4*)&st_r[uidx + 16*j] = r1 - kv[j];
                    p[j] = y[j] + hstep*kv[j] - h3*r1;
                }
            } else if (e == 2) {     // k3: U+=3k3, p4 = y+h(k1-k2+k3)
#pragma unroll
                for (int j = 0; j < 2; ++j) {
                    floatx4 D = *(const floatx4*)&st_r[uidx + 16*j];
                    floatx4 U = *(const floatx4*)&st_u[uidx + 16*j];
                    *(floatx4*)&st_u[uidx + 16*j] = U + 3.0f*kv[j];
                    p[j] = y[j] + hstep*(D + kv[j]);
                }
            } else {                 // k4: y += h/8 (U + k4); store; p = y
                const float h8 = hstep*0.125f;
#pragma unroll
                for (int j = 0; j < 2; ++j) {
                    floatx4 U = *(const floatx4*)&st_u[uidx + 16*j];
                    y[j] = y[j] + h8*(U + kv[j]);
                    p[j] = y[j];
                }
                if (n16 < GROWS) {
                    const int gr = blk*24 + g*GROWS + n16;
                    float* po = out + ((size_t)(gr*50 + s + 1))*DIM + 32*wb + 4*quad;
                    *(floatx4*)&po[0]  = p[0];
                    *(floatx4*)&po[16] = p[1];
                }
            }
            publish_point(g, p);
        };

        const int hbase = n16*HH + quad*8;
        __syncthreads();                      // matches A prologue barrier
        for (int tau = 0; tau < NTAU; ++tau) {
            if (tau > 0) {
                const int g  = 1 - (tau & 1);
                const int ei = (tau - 1 - g) >> 1;   // per-group eval counter
                const int e  = ei & 3;
                const int s  = ei >> 2;
                const float hstep = ts_l[s+1] - ts_l[s];
                floatx4 bM[2], bC[2];
                bM[0] = bias2[0]; bM[1] = bias2[1];
                bC[0] = (floatx4){0.f,0.f,0.f,0.f};
                bC[1] = (floatx4){0.f,0.f,0.f,0.f};
                __builtin_amdgcn_s_setprio(1);
#pragma unroll
                for (int kt = 0; kt < 8; ++kt) {
                    half8 hbh = *(const half8*)&hfh[g][hbase + kt*32];
                    half8 hbl = *(const half8*)&hfl[g][hbase + kt*32];
#pragma unroll
                    for (int j = 0; j < 2; ++j) {
                        bM[j] = __builtin_amdgcn_mfma_f32_16x16x32_f16(w2h[j][kt], hbh, bM[j], 0,0,0);
                        bC[j] = __builtin_amdgcn_mfma_f32_16x16x32_f16(w2l[j][kt], hbh, bC[j], 0,0,0);
                        bC[j] = __builtin_amdgcn_mfma_f32_16x16x32_f16(w2h[j][kt], hbl, bC[j], 0,0,0);
                    }
                }
                __builtin_amdgcn_s_setprio(0);
                floatx4 kv[2];
#pragma unroll
                for (int j = 0; j < 2; ++j)
#pragma unroll
                    for (int r = 0; r < 4; ++r)
                        kv[j][r] = bM[j][r] + LOINV*bC[j][r];
                if (g == 0) fold_build(yg0, kv, 0, e, hstep, s);
                else        fold_build(yg1, kv, 1, e, hstep, s);
            }
            __syncthreads();
        }
    }
}

extern "C" void kernel_launch(void* const* d_in, const int* in_sizes, int n_in,
                              void* d_out, int out_size, void* d_ws, size_t ws_size,
                              hipStream_t stream) {
    const float* fp     = (const float*)d_in[0];
    const float* tsteps = (const float*)d_in[1];
    const float* W1     = (const float*)d_in[2];
    const float* b1     = (const float*)d_in[3];
    const float* W2     = (const float*)d_in[4];
    const float* b2     = (const float*)d_in[5];
    float* out          = (float*)d_out;

    ode_pipe_kernel<<<NBLK, 512, 0, stream>>>(fp, tsteps, W1, b1, W2, b2, out);
}

// Round 3
// 653.299 us; speedup vs baseline: 1.0953x; 1.0537x over previous
//
#include <hip/hip_runtime.h>

// DiffeqSolver: 49 RK4(3/8) steps of y' = W2 @ tanh(W1 @ y + b1) + b2
// 6144 rows, dim 128 (123+5 aug), hidden 256. Output (3,2048,50,128) fp32.
//
// Round 6: 16-wave staggered producer/consumer + conflict-free frag-linear LDS.
//  - 256 blocks x 1024 threads (16 waves, 4/SIMD, 1 block/CU). Waves 0-7 (A)
//    hold 2 h-tiles of W1 each (64 VGPR); waves 8-15 (B) hold 1 d-tile of W2
//    (64 VGPR). Both branches fit the 128-VGPR cap of launch_bounds(1024,4)
//    -> no spill (round 5's fatal flaw: 4-tile A waves needed ~170).
//  - Two 12-row pipeline groups (round-4 skew): interval tau: A computes
//    H(g=tau&1) while B computes K+fold+publish(1-g). Each SIMD hosts 2 A +
//    2 B waves on OPPOSITE groups -> one wave's VALU tail overlaps the other
//    three waves' MFMA bursts (round 4's serial tail: 1860 MFMA + 1600 VALU
//    = 4060 cy/interval at only 2 waves/SIMD).
//  - Frag-linear LDS [group][kt][quad][n16][j]: every b128 frag read is 64
//    lanes x contiguous 1024 B = zero bank conflict (old YH/HH strides gave
//    2-way on every read, 5.8e7 conflict cycles). Publishes are per-lane b64
//    into disjoint 8B slots. One barrier per interval.
//  - Split precision unchanged (validated): x = hi(f16) + 2^-11*lo(f16),
//    3 MFMA products; correction accumulators split for dep-chain ILP.

typedef _Float16 half8  __attribute__((ext_vector_type(8)));
typedef _Float16 half4  __attribute__((ext_vector_type(4)));
typedef float    floatx4 __attribute__((ext_vector_type(4)));

#define NBLK 256
#define DIM  128
#define HID  256
#define ROWS 24           // rows per block (2 groups x 12)
#define GROWS 12
#define NTAU 393          // 2*196 evals + 1 pipeline bubble
#define LOSCALE 2048.0f
#define LOINV   (1.0f/2048.0f)

__device__ __forceinline__ float fast_tanh(float x) {
    float e = __expf(2.0f * x);
    return 1.0f - 2.0f * __builtin_amdgcn_rcpf(e + 1.0f);
}

struct h2 { _Float16 hi, lo; };
__device__ __forceinline__ h2 split16(float v) {
    h2 r;
    r.hi = (_Float16)v;
    r.lo = (_Float16)((v - (float)r.hi) * LOSCALE);
    return r;
}

__global__ __launch_bounds__(1024, 4)
void ode_fl_kernel(const float* __restrict__ fp,      // (3,2048,123)
                   const float* __restrict__ tsteps,  // (50)
                   const float* __restrict__ W1,      // (256,128)
                   const float* __restrict__ b1,      // (256)
                   const float* __restrict__ W2,      // (128,256)
                   const float* __restrict__ b2,      // (128)
                   float* __restrict__ out)           // (3,2048,50,128)
{
    // frag-linear: element (batch n, k) at (k>>5)*512 + ((k>>3)&3)*128 + n*8 + (k&7)
    __shared__ __align__(16) _Float16 yfh[2][2048], yfl[2][2048];  // k=d  (128)
    __shared__ __align__(16) _Float16 hfh[2][4096], hfl[2][4096];  // k=h  (256)
    __shared__ float ts_l[64];

    const int tid  = threadIdx.x;
    const int wave = tid >> 6;
    const int lane = tid & 63;
    const int n16  = lane & 15;
    const int quad = lane >> 4;
    const int blk  = blockIdx.x;

    if (tid < 50) ts_l[tid] = tsteps[tid];

    if (wave < 8) {
        // ============ producer A: H^T = tanh(W1 . Y^T + b1), 2 tiles =======
        const int a = wave;                    // h-rows [32a, 32a+32)
        half8 w1h[2][4], w1l[2][4];            // [i][kt]
        floatx4 bias1[2];
#pragma unroll
        for (int i = 0; i < 2; ++i) {
            bias1[i] = *(const floatx4*)(b1 + 32*a + 16*i + 4*quad);
#pragma unroll
            for (int kt = 0; kt < 4; ++kt) {
                const float* p = W1 + (32*a + 16*i + n16)*DIM + kt*32 + quad*8;
#pragma unroll
                for (int j = 0; j < 8; ++j) {
                    h2 sp = split16(p[j]);
                    w1h[i][kt][j] = sp.hi;
                    w1l[i][kt][j] = sp.lo;
                }
            }
        }
        const int yrd  = quad*128 + n16*8;               // + kt*512
        const int hwr  = a*512 + n16*8 + 4*(quad&1);     // + ((2i+hq)&3)*128
        const int hq   = quad >> 1;
        __syncthreads();                                 // prologue: yf ready
        for (int tau = 0; tau < NTAU; ++tau) {
            if (tau < NTAU-1) {
                const int g = tau & 1;
                floatx4 aM[2], aC[2], aD[2];
#pragma unroll
                for (int i = 0; i < 2; ++i) {
                    aM[i] = bias1[i];
                    aC[i] = (floatx4){0.f,0.f,0.f,0.f};
                    aD[i] = (floatx4){0.f,0.f,0.f,0.f};
                }
                __builtin_amdgcn_s_setprio(1);
#pragma unroll
                for (int kt = 0; kt < 4; ++kt) {
                    half8 ybh = *(const half8*)&yfh[g][kt*512 + yrd];
                    half8 ybl = *(const half8*)&yfl[g][kt*512 + yrd];
#pragma unroll
                    for (int i = 0; i < 2; ++i) {
                        aM[i] = __builtin_amdgcn_mfma_f32_16x16x32_f16(w1h[i][kt], ybh, aM[i], 0,0,0);
                        aC[i] = __builtin_amdgcn_mfma_f32_16x16x32_f16(w1l[i][kt], ybh, aC[i], 0,0,0);
                        aD[i] = __builtin_amdgcn_mfma_f32_16x16x32_f16(w1h[i][kt], ybl, aD[i], 0,0,0);
                    }
                }
                __builtin_amdgcn_s_setprio(0);
#pragma unroll
                for (int i = 0; i < 2; ++i) {
                    half4 th, tl;
#pragma unroll
                    for (int r = 0; r < 4; ++r) {
                        const float v = aM[i][r] + LOINV*(aC[i][r] + aD[i][r]);
                        h2 sp = split16(fast_tanh(v));
                        th[r] = sp.hi; tl[r] = sp.lo;
                    }
                    const int off = hwr + ((2*i + hq) & 3)*128;
                    *(half4*)&hfh[g][off] = th;
                    *(half4*)&hfl[g][off] = tl;
                }
            }
            __syncthreads();
        }
    } else {
        // ====== consumer B: K^T = W2 . H^T + b2 ; RK fold ; publish yf =====
        const int wb = wave - 8;               // d-rows [16wb, 16wb+16)
        half8 w2h[8], w2l[8];                  // [kt]
        floatx4 bias2 = *(const floatx4*)(b2 + 16*wb + 4*quad);
#pragma unroll
        for (int kt = 0; kt < 8; ++kt) {
            const float* p = W2 + (16*wb + n16)*HID + kt*32 + quad*8;
#pragma unroll
            for (int j = 0; j < 8; ++j) {
                h2 sp = split16(p[j]);
                w2h[kt][j] = sp.hi;
                w2l[kt][j] = sp.lo;
            }
        }
        // per-lane state: d = 16wb + 4quad + r, row n16 (valid n16 < 12)
        const int d0 = 16*wb + 4*quad;
        floatx4 yg0 = (floatx4){0.f,0.f,0.f,0.f};
        floatx4 yg1 = (floatx4){0.f,0.f,0.f,0.f};
        floatx4 r10 = yg0, r11 = yg0, uu0 = yg0, uu1 = yg0;
        if (n16 < GROWS) {
#pragma unroll
            for (int r = 0; r < 4; ++r) {
                const int d = d0 + r;
                if (d < 123) {
                    yg0[r] = fp[(blk*ROWS + n16)*123 + d];
                    yg1[r] = fp[(blk*ROWS + GROWS + n16)*123 + d];
                }
            }
            // t = 0 output
            float* p0 = out + ((size_t)(blk*ROWS + n16)*50)*DIM + d0;
            float* p1 = out + ((size_t)(blk*ROWS + GROWS + n16)*50)*DIM + d0;
            *(floatx4*)p0 = yg0;
            *(floatx4*)p1 = yg1;
        }

        const int ywr = (wb>>1)*512 + ((2*wb + (quad>>1)) & 3)*128 + n16*8 + 4*(quad&1);
        auto publish = [&](int g, floatx4 p) {
            half4 hi, lo;
#pragma unroll
            for (int r = 0; r < 4; ++r) {
                h2 sp = split16(p[r]);
                hi[r] = sp.hi; lo[r] = sp.lo;
            }
            *(half4*)&yfh[g][ywr] = hi;
            *(half4*)&yfl[g][ywr] = lo;
        };
        publish(0, yg0);                       // e0 eval points = y0
        publish(1, yg1);

        auto fold = [&](floatx4 &yg, floatx4 &r1, floatx4 &uu, floatx4 kv,
                        int g, int e, int s, float hstep) {
            floatx4 p;
            const float h3 = hstep * (1.0f/3.0f);
            if (e == 0) {            // k1: save, p2 = y + h/3 k1
                r1 = kv;
                p  = yg + h3*kv;
            } else if (e == 1) {     // k2: U=k1+3k2, D=k1-k2, p3 = y+h k2-h/3 k1
                uu = r1 + 3.0f*kv;
                p  = yg + hstep*kv - h3*r1;
                r1 = r1 - kv;
            } else if (e == 2) {     // k3: U+=3k3, p4 = y+h(D+k3)
                uu = uu + 3.0f*kv;
                p  = yg + hstep*(r1 + kv);
            } else {                 // k4: y += h/8 (U+k4); store
                yg = yg + hstep*0.125f*(uu + kv);
                p  = yg;
                if (n16 < GROWS) {
                    const int gr = blk*ROWS + g*GROWS + n16;
                    float* po = out + ((size_t)(gr*50 + s + 1))*DIM + d0;
                    *(floatx4*)po = p;
                }
            }
            publish(g, p);
        };

        const int hrd = quad*128 + n16*8;                // + kt*512
        __syncthreads();                                 // prologue
        for (int tau = 0; tau < NTAU; ++tau) {
            if (tau > 0) {
                const int g  = 1 - (tau & 1);
                const int ei = (tau - 1 - g) >> 1;
                const int e  = ei & 3;
                const int s  = ei >> 2;
                const float hstep = ts_l[s+1] - ts_l[s];
                floatx4 bM = bias2;
                floatx4 bC = (floatx4){0.f,0.f,0.f,0.f};
                floatx4 bD = (floatx4){0.f,0.f,0.f,0.f};
                __builtin_amdgcn_s_setprio(1);
#pragma unroll
                for (int kt = 0; kt < 8; ++kt) {
                    half8 hbh = *(const half8*)&hfh[g][kt*512 + hrd];
                    half8 hbl = *(const half8*)&hfl[g][kt*512 + hrd];
                    bM = __builtin_amdgcn_mfma_f32_16x16x32_f16(w2h[kt], hbh, bM, 0,0,0);
                    bC = __builtin_amdgcn_mfma_f32_16x16x32_f16(w2l[kt], hbh, bC, 0,0,0);
                    bD = __builtin_amdgcn_mfma_f32_16x16x32_f16(w2h[kt], hbl, bD, 0,0,0);
                }
                __builtin_amdgcn_s_setprio(0);
                floatx4 kv;
#pragma unroll
                for (int r = 0; r < 4; ++r)
                    kv[r] = bM[r] + LOINV*(bC[r] + bD[r]);
                if (g == 0) fold(yg0, r10, uu0, kv, 0, e, s, hstep);
                else        fold(yg1, r11, uu1, kv, 1, e, s, hstep);
            }
            __syncthreads();
        }
    }
}

extern "C" void kernel_launch(void* const* d_in, const int* in_sizes, int n_in,
                              void* d_out, int out_size, void* d_ws, size_t ws_size,
                              hipStream_t stream) {
    const float* fp     = (const float*)d_in[0];
    const float* tsteps = (const float*)d_in[1];
    const float* W1     = (const float*)d_in[2];
    const float* b1     = (const float*)d_in[3];
    const float* W2     = (const float*)d_in[4];
    const float* b2     = (const float*)d_in[5];
    float* out          = (float*)d_out;

    ode_fl_kernel<<<NBLK, 1024, 0, stream>>>(fp, tsteps, W1, b1, W2, b2, out);
}